// Round 23
// baseline (52906.189 us; speedup 1.0000x reference)
//
#include <hip/hip_runtime.h>
#include <hip/hip_bf16.h>
#include <stdint.h>

#define BATCH   256
#define T_STEPS 100
#define IN_DIM  700
#define H_DIM   1024
#define OUT_DIM 20

// Exactness contract (validated R21/R22): per output element, cur = serial
// ascending fmaf chain in k, straight 512-chunks, one f32 add per chunk join.
// LIF: rst=(m>thr)?thr:0; v=0.5f*m+cur; v-=rst; spk=(v>thr).

// ---------------- K0: layer-0, all t; async-staged, 512 blocks -------------
// 1D grid 512: wg&7 = b-group (32 rows, XCD-affine), wg>>3 = n-block (16 n).
// 256 thr: wv=tid>>6, nl=ln&15 (n), bq=ln>>4; rows br = bq+4wv+16j, j=0,1.
__global__ __launch_bounds__(256) void k0_gemm_lif(
    const float* __restrict__ x,      // [256][100][700]
    const float* __restrict__ W0,     // [1024][700]
    const float* __restrict__ thr_p,
    uint16_t* __restrict__ spk0_bits) // [100][256][64] words; bit i = n0+i
{
    __shared__ __align__(16) float Wt[16 * 708];
    __shared__ __align__(16) float At[32 * 132];

    const int tid = threadIdx.x;
    const int wg  = blockIdx.x;
    const int n0  = (wg >> 3) * 16;
    const int b0  = (wg & 7) * 32;

    {   // W tile 16 x 700 (175 float4/row)
        const int r = tid >> 4, c16 = tid & 15;
        const float* src = W0 + (size_t)(n0 + r) * IN_DIM;
        float* dst = Wt + r * 708;
        for (int f = c16; f < 175; f += 16)
            ((float4*)dst)[f] = ((const float4*)src)[f];
    }

    // prefetch mapping: row pr = tid>>3 (32 rows), f4 base (tid&7)*4 (64 B)
    const int pr  = tid >> 3;
    const int pf4 = (tid & 7) * 4;
    const float* xrow = x + (size_t)(b0 + pr) * T_STEPS * IN_DIM;

    float4 pf[4];
#pragma unroll
    for (int u = 0; u < 4; ++u)                 // prefetch (t=0, c=0); k<=127
        pf[u] = *(const float4*)(xrow + (pf4 + u) * 4);

    __syncthreads();                            // Wt ready

    const int wv = tid >> 6, ln = tid & 63, nl = ln & 15, bq = ln >> 4;
    const float thr = *thr_p;
    float m[2] = {0.f, 0.f};

    for (int t = 0; t < T_STEPS; ++t) {
        float ps[2] = {0.f, 0.f};
        float s[2]  = {0.f, 0.f};
        for (int c = 0; c < 6; ++c) {
            __syncthreads();                    // prev chunk compute done
            {   // commit prefetched chunk to LDS (waits its loads implicitly)
                float* dst = At + pr * 132 + pf4 * 4;
#pragma unroll
                for (int u = 0; u < 4; ++u)
                    ((float4*)dst)[u] = pf[u];
            }
            {   // issue next chunk's loads; they fly during this compute
                int nt = t, nc = c + 1;
                if (nc == 6) { nc = 0; ++nt; }
                if (nt < T_STEPS) {
                    const float* base = xrow + (size_t)nt * IN_DIM + nc * 128;
#pragma unroll
                    for (int u = 0; u < 4; ++u) {
                        const int k = (pf4 + u) * 4;
                        pf[u] = (nc * 128 + k + 3 < IN_DIM)
                              ? *(const float4*)(base + k)
                              : make_float4(0.f, 0.f, 0.f, 0.f);
                    }
                }
            }
            __syncthreads();                    // At ready
            const int nk4 = (c == 5) ? 15 : 32; // chunk 5: k in [640,700)
            const float4* wrow  = (const float4*)(Wt + nl * 708 + c * 128);
            const float4* arow0 = (const float4*)(At + (bq + 4 * wv) * 132);
            const float4* arow1 = (const float4*)(At + (bq + 4 * wv + 16) * 132);
            for (int k4 = 0; k4 < nk4; ++k4) {
                const float4 w4 = wrow[k4];
                const float4 a0 = arow0[k4];
                const float4 a1 = arow1[k4];
                ps[0] = __builtin_fmaf(a0.x, w4.x, ps[0]);
                ps[0] = __builtin_fmaf(a0.y, w4.y, ps[0]);
                ps[0] = __builtin_fmaf(a0.z, w4.z, ps[0]);
                ps[0] = __builtin_fmaf(a0.w, w4.w, ps[0]);
                ps[1] = __builtin_fmaf(a1.x, w4.x, ps[1]);
                ps[1] = __builtin_fmaf(a1.y, w4.y, ps[1]);
                ps[1] = __builtin_fmaf(a1.z, w4.z, ps[1]);
                ps[1] = __builtin_fmaf(a1.w, w4.w, ps[1]);
            }
            if (c == 3 || c == 5) {             // BLIS joins at k=512, 700
                s[0] += ps[0]; ps[0] = 0.f;
                s[1] += ps[1]; ps[1] = 0.f;
            }
        }
#pragma unroll
        for (int j = 0; j < 2; ++j) {
            const float rst = (m[j] > thr) ? thr : 0.f;
            float v = 0.5f * m[j] + s[j];
            v = v - rst;
            m[j] = v;
        }
#pragma unroll
        for (int j = 0; j < 2; ++j) {
            const unsigned long long mask = __ballot(m[j] > thr);
            if (nl == 0) {
                const int br = bq + 4 * wv + 16 * j;
                spk0_bits[((size_t)t * BATCH + (b0 + br)) * 64 + (wg >> 3)] =
                    (uint16_t)((mask >> (16 * bq)) & 0xFFFFull);
            }
        }
    }
}

// ---------------- K1: layer-1 GEMM+LIF, all t (A from spk0 bits) -----------
__global__ __launch_bounds__(256) void k1_gemm_lif(
    const uint16_t* __restrict__ spk0_bits,
    const float* __restrict__ W1,     // [1024][1024]
    const float* __restrict__ thr_p,
    uint16_t* __restrict__ spk1_bits)
{
    __shared__ __align__(16) float Wt[16 * 1028];
    __shared__ __align__(16) float At[64 * 132];

    const int tid = threadIdx.x;
    const int n0 = blockIdx.x * 16;
    const int b0 = blockIdx.y * 64;

    {   // W tile 16 x 1024 (256 f4/row)
        const int r = tid >> 4, c = tid & 15;
        const float* src = W1 + (size_t)(n0 + r) * H_DIM;
        float* dst = Wt + r * 1028;
        for (int f = c; f < 256; f += 16)
            ((float4*)dst)[f] = ((const float4*)src)[f];
    }
    __syncthreads();

    const int wv = tid >> 6, ln = tid & 63, nl = ln & 15, bq = ln >> 4;
    const float thr = *thr_p;
    float m[4] = {0.f, 0.f, 0.f, 0.f};

    for (int t = 0; t < T_STEPS; ++t) {
        float ps[4] = {0.f, 0.f, 0.f, 0.f};
        float s[4]  = {0.f, 0.f, 0.f, 0.f};
        for (int c = 0; c < 8; ++c) {          // joins after c3 (512), c7 (1024)
            __syncthreads();
            {   // stage A chunk from bits: 512 u16 words, 2 per thread
#pragma unroll
                for (int u = 0; u < 2; ++u) {
                    const int widx = tid * 2 + u;
                    const int r = widx >> 3, wi = widx & 7;
                    const uint32_t w =
                        spk0_bits[((size_t)t * BATCH + (b0 + r)) * 64 + c * 8 + wi];
                    float* dst = At + r * 132 + wi * 16;
#pragma unroll
                    for (int i = 0; i < 16; ++i)
                        dst[i] = ((w >> i) & 1u) ? 1.0f : 0.0f;
                }
            }
            __syncthreads();
            const float* wrow = Wt + nl * 1028 + c * 128;
            for (int k4 = 0; k4 < 32; ++k4) {
                const float4 w4 = ((const float4*)wrow)[k4];
#pragma unroll
                for (int j = 0; j < 4; ++j) {
                    const int br = 16 * wv + bq + 4 * j;
                    const float4 a4 = *(const float4*)(At + br * 132 + k4 * 4);
                    ps[j] = __builtin_fmaf(a4.x, w4.x, ps[j]);
                    ps[j] = __builtin_fmaf(a4.y, w4.y, ps[j]);
                    ps[j] = __builtin_fmaf(a4.z, w4.z, ps[j]);
                    ps[j] = __builtin_fmaf(a4.w, w4.w, ps[j]);
                }
            }
            if (c == 3 || c == 7) {
#pragma unroll
                for (int j = 0; j < 4; ++j) { s[j] += ps[j]; ps[j] = 0.f; }
            }
        }
        float mn[4];
#pragma unroll
        for (int j = 0; j < 4; ++j) {
            const float rst = (m[j] > thr) ? thr : 0.f;
            float v = 0.5f * m[j] + s[j];
            v = v - rst;
            m[j] = v; mn[j] = v;
        }
#pragma unroll
        for (int j = 0; j < 4; ++j) {
            const unsigned long long mask = __ballot(mn[j] > thr);
            if (nl == 0) {
                const int br = 16 * wv + bq + 4 * j;
                spk1_bits[((size_t)t * BATCH + (b0 + br)) * 64 + blockIdx.x] =
                    (uint16_t)((mask >> (16 * bq)) & 0xFFFFull);
            }
        }
    }
}

// ---------------- K2a: output-layer currents for all t ---------------------
__global__ __launch_bounds__(256) void k2a_gemm(
    const uint16_t* __restrict__ spk1_bits,
    const float* __restrict__ W2,     // [20][1024]
    float* __restrict__ cur2)         // [100*256][20]
{
    const int gid = blockIdx.x * 256 + threadIdx.x;
    const int q = gid / OUT_DIM, n = gid % OUT_DIM;
    if (q >= T_STEPS * BATCH) return;

    const uint16_t* bits = spk1_bits + (size_t)q * 64;
    const float* w = W2 + (size_t)n * H_DIM;
    float s = 0.f, ps = 0.f;
    for (int wi = 0; wi < 64; ++wi) {
        const uint32_t bw = bits[wi];
        const float4* w4p = (const float4*)(w + wi * 16);
#pragma unroll
        for (int f = 0; f < 4; ++f) {
            const float4 w4 = w4p[f];
            const int base = f * 4;
            ps += ((bw >> (base + 0)) & 1u) ? w4.x : 0.0f;
            ps += ((bw >> (base + 1)) & 1u) ? w4.y : 0.0f;
            ps += ((bw >> (base + 2)) & 1u) ? w4.z : 0.0f;
            ps += ((bw >> (base + 3)) & 1u) ? w4.w : 0.0f;
        }
        if (wi == 31) { s += ps; ps = 0.f; }   // panel join at k=512
    }
    s += ps;                                    // final join at k=1024
    cur2[(size_t)q * OUT_DIM + n] = s;
}

// ---------------- K2b: output-layer LIF recurrence + final writes ----------
__global__ __launch_bounds__(256) void k2b_lif_out(
    const float* __restrict__ cur2,
    const float* __restrict__ thr_p,
    float* __restrict__ out)           // [spk: 100*256*20][mem: 100*256*20]
{
    const int idx = blockIdx.x * 256 + threadIdx.x;
    if (idx >= BATCH * OUT_DIM) return;
    const float thr = *thr_p;
    const size_t stride = (size_t)BATCH * OUT_DIM;
    float m = 0.f;
    for (int t = 0; t < T_STEPS; ++t) {
        const float cur = cur2[(size_t)t * stride + idx];
        const float rst = (m > thr) ? thr : 0.f;
        float v = 0.5f * m + cur;
        v = v - rst;
        m = v;
        out[(size_t)t * stride + idx] = (v > thr) ? 1.0f : 0.0f;
        out[(size_t)T_STEPS * stride + (size_t)t * stride + idx] = v;
    }
}

extern "C" void kernel_launch(void* const* d_in, const int* in_sizes, int n_in,
                              void* d_out, int out_size, void* d_ws, size_t ws_size,
                              hipStream_t stream)
{
    const float* x    = (const float*)d_in[0];
    const float* W0   = (const float*)d_in[1];
    const float* W1   = (const float*)d_in[2];
    const float* W2   = (const float*)d_in[3];
    const float* thr0 = (const float*)d_in[4];
    const float* thr1 = (const float*)d_in[5];
    const float* thr2 = (const float*)d_in[6];

    // ws: spk0 bits 3.28 MB | spk1 bits 3.28 MB | cur2 2.05 MB (= 8.6 MB)
    // every element written before read each call -> no memset needed
    uint16_t* spk0_bits = (uint16_t*)d_ws;
    uint16_t* spk1_bits = spk0_bits + (size_t)T_STEPS * BATCH * 64;
    float*    cur2      = (float*)(spk1_bits + (size_t)T_STEPS * BATCH * 64);

    k0_gemm_lif<<<512, 256, 0, stream>>>(x, W0, thr0, spk0_bits);
    k1_gemm_lif<<<dim3(H_DIM / 16, BATCH / 64), 256, 0, stream>>>(
        spk0_bits, W1, thr1, spk1_bits);
    k2a_gemm<<<(T_STEPS * BATCH * OUT_DIM) / 256, 256, 0, stream>>>(
        spk1_bits, W2, cur2);
    k2b_lif_out<<<(BATCH * OUT_DIM + 255) / 256, 256, 0, stream>>>(
        cur2, thr2, (float*)d_out);
}

// Round 24
// 4231.653 us; speedup vs baseline: 12.5025x; 12.5025x over previous
//
#include <hip/hip_runtime.h>
#include <hip/hip_bf16.h>
#include <stdint.h>

#define BATCH   256
#define T_STEPS 100
#define IN_DIM  700
#define H_DIM   1024
#define OUT_DIM 20
#define TC      4      // timesteps per L0 chunk
#define NCHUNK  25     // 100 / TC

// Exactness contract (validated R21/R22): per output element, cur = serial
// ascending fmaf chain in k, straight 512-chunks, one f32 add per chunk join
// (first join exact from 0). LIF: rst=(m>thr)?thr:0; v=0.5f*m+cur; v-=rst;
// spk=(v>thr).  K=700 panels [512,188]; K=1024 panels [512,512].

// ---------------- K0a: layer-0 currents, pure GEMM over one t-chunk --------
// M = 1024 rows (mrow = b*TC + ti), N = 1024, K = 700. 64x64 tile, 256 thr,
// each computes rows m0+ty+16i x cols n0+tx+16j (i,j=0..3).
__global__ __launch_bounds__(256) void k0a_gemm(
    const float* __restrict__ x,      // [256][100][700]
    const float* __restrict__ W0,     // [1024][700]
    float* __restrict__ cur0,         // [1024][1024] chunk
    int tc)
{
    __shared__ __align__(16) float As[64][68];
    __shared__ __align__(16) float Ws[64][68];   // f4-swizzled: slot = f4 ^ (r&7)

    const int tid = threadIdx.x;
    const int n0 = blockIdx.x * 64;
    const int m0 = blockIdx.y * 64;
    const int tx = tid & 15, ty = tid >> 4;

    float ps[4][4], s[4][4];
#pragma unroll
    for (int i = 0; i < 4; ++i)
#pragma unroll
        for (int j = 0; j < 4; ++j) { ps[i][j] = 0.f; s[i][j] = 0.f; }

    const int sr  = tid >> 2;            // staging row 0..63
    const int sf0 = (tid & 3) * 4;       // staging f4 base

#pragma unroll 1
    for (int c = 0; c < 11; ++c) {       // 64-k chunks; panel joins c=7, c=10
        __syncthreads();
        {   // stage A row sr: logical f4 sf0..sf0+3 (linear layout)
            const int mrow = m0 + sr;
            const int b = mrow >> 2, ti = mrow & 3;
            const float* src = x + ((size_t)b * T_STEPS + tc * TC + ti) * IN_DIM;
#pragma unroll
            for (int u = 0; u < 4; ++u) {
                const int f4 = sf0 + u;
                const int k = c * 64 + f4 * 4;
                const float4 v = (k < IN_DIM) ? *(const float4*)(src + k)
                                              : make_float4(0.f, 0.f, 0.f, 0.f);
                *(float4*)&As[sr][f4 * 4] = v;
            }
            // stage W row sr (swizzled slot)
            const float* wsrc = W0 + (size_t)(n0 + sr) * IN_DIM;
#pragma unroll
            for (int u = 0; u < 4; ++u) {
                const int f4 = sf0 + u;
                const int k = c * 64 + f4 * 4;
                const float4 v = (k < IN_DIM) ? *(const float4*)(wsrc + k)
                                              : make_float4(0.f, 0.f, 0.f, 0.f);
                *(float4*)&Ws[sr][(f4 ^ (sr & 7)) * 4] = v;
            }
        }
        __syncthreads();

        const int kmax4 = (c == 10) ? 15 : 16;   // chunk 10: k in [640,700)
        const int wxor = tx & 7;                  // row&7 for rows tx+16j
        for (int k4 = 0; k4 < kmax4; ++k4) {
            float4 av[4], wv[4];
#pragma unroll
            for (int i = 0; i < 4; ++i)
                av[i] = *(const float4*)&As[ty + 16 * i][k4 * 4];
#pragma unroll
            for (int j = 0; j < 4; ++j)
                wv[j] = *(const float4*)&Ws[tx + 16 * j][(k4 ^ wxor) * 4];
#pragma unroll
            for (int i = 0; i < 4; ++i)
#pragma unroll
                for (int j = 0; j < 4; ++j) {
                    ps[i][j] = __builtin_fmaf(av[i].x, wv[j].x, ps[i][j]);
                    ps[i][j] = __builtin_fmaf(av[i].y, wv[j].y, ps[i][j]);
                    ps[i][j] = __builtin_fmaf(av[i].z, wv[j].z, ps[i][j]);
                    ps[i][j] = __builtin_fmaf(av[i].w, wv[j].w, ps[i][j]);
                }
        }
        if (c == 7 || c == 10) {         // BLIS joins at k=512 and k=700
#pragma unroll
            for (int i = 0; i < 4; ++i)
#pragma unroll
                for (int j = 0; j < 4; ++j) { s[i][j] += ps[i][j]; ps[i][j] = 0.f; }
        }
    }

#pragma unroll
    for (int i = 0; i < 4; ++i) {
        const int mrow = m0 + ty + 16 * i;
#pragma unroll
        for (int j = 0; j < 4; ++j)
            cur0[(size_t)mrow * H_DIM + n0 + tx + 16 * j] = s[i][j];
    }
}

// ---------------- lif0: layer-0 recurrence over one t-chunk ----------------
__global__ __launch_bounds__(256) void lif0(
    const float* __restrict__ cur0,   // [1024][1024] chunk (mrow = b*TC+ti)
    float* __restrict__ m0state,      // [256*1024]
    const float* __restrict__ thr_p,
    uint16_t* __restrict__ spk0_bits, // [100][256][64]
    int tc)
{
    const int tid = threadIdx.x;
    const int n = blockIdx.x * 256 + tid;   // grid.x = 4
    const int b = blockIdx.y;
    const int wv = tid >> 6, ln = tid & 63;
    const float thr = *thr_p;

    float m = m0state[(size_t)b * H_DIM + n];
#pragma unroll
    for (int ti = 0; ti < TC; ++ti) {
        const int t = tc * TC + ti;
        const float cur = cur0[((size_t)(b * TC + ti)) * H_DIM + n];
        const float rst = (m > thr) ? thr : 0.f;
        float v = 0.5f * m + cur;
        v = v - rst;
        m = v;
        const unsigned long long mask = __ballot(v > thr);
        if ((ln & 15) == 0) {
            const int q = ln >> 4;
            spk0_bits[((size_t)t * BATCH + b) * 64 + blockIdx.x * 16 + wv * 4 + q] =
                (uint16_t)((mask >> (16 * q)) & 0xFFFFull);
        }
    }
    m0state[(size_t)b * H_DIM + n] = m;
}

// ---------------- K1: layer-1 GEMM+LIF, all t (A from spk0 bits) -----------
__global__ __launch_bounds__(256) void k1_gemm_lif(
    const uint16_t* __restrict__ spk0_bits,
    const float* __restrict__ W1,     // [1024][1024]
    const float* __restrict__ thr_p,
    uint16_t* __restrict__ spk1_bits)
{
    __shared__ __align__(16) float Wt[16 * 1028];
    __shared__ __align__(16) float At[64 * 132];

    const int tid = threadIdx.x;
    const int n0 = blockIdx.x * 16;
    const int b0 = blockIdx.y * 64;

    {   // W tile 16 x 1024 (256 f4/row)
        const int r = tid >> 4, c = tid & 15;
        const float* src = W1 + (size_t)(n0 + r) * H_DIM;
        float* dst = Wt + r * 1028;
        for (int f = c; f < 256; f += 16)
            ((float4*)dst)[f] = ((const float4*)src)[f];
    }
    __syncthreads();

    const int wv = tid >> 6, ln = tid & 63, nl = ln & 15, bq = ln >> 4;
    const float thr = *thr_p;
    float m[4] = {0.f, 0.f, 0.f, 0.f};

    for (int t = 0; t < T_STEPS; ++t) {
        float ps[4] = {0.f, 0.f, 0.f, 0.f};
        float s[4]  = {0.f, 0.f, 0.f, 0.f};
        for (int c = 0; c < 8; ++c) {          // joins after c3 (512), c7 (1024)
            __syncthreads();
            {   // stage A chunk from bits: 512 u16 words, 2 per thread
#pragma unroll
                for (int u = 0; u < 2; ++u) {
                    const int widx = tid * 2 + u;
                    const int r = widx >> 3, wi = widx & 7;
                    const uint32_t w =
                        spk0_bits[((size_t)t * BATCH + (b0 + r)) * 64 + c * 8 + wi];
                    float* dst = At + r * 132 + wi * 16;
#pragma unroll
                    for (int i = 0; i < 16; ++i)
                        dst[i] = ((w >> i) & 1u) ? 1.0f : 0.0f;
                }
            }
            __syncthreads();
            const float* wrow = Wt + nl * 1028 + c * 128;
            for (int k4 = 0; k4 < 32; ++k4) {
                const float4 w4 = ((const float4*)wrow)[k4];
#pragma unroll
                for (int j = 0; j < 4; ++j) {
                    const int br = 16 * wv + bq + 4 * j;
                    const float4 a4 = *(const float4*)(At + br * 132 + k4 * 4);
                    ps[j] = __builtin_fmaf(a4.x, w4.x, ps[j]);
                    ps[j] = __builtin_fmaf(a4.y, w4.y, ps[j]);
                    ps[j] = __builtin_fmaf(a4.z, w4.z, ps[j]);
                    ps[j] = __builtin_fmaf(a4.w, w4.w, ps[j]);
                }
            }
            if (c == 3 || c == 7) {
#pragma unroll
                for (int j = 0; j < 4; ++j) { s[j] += ps[j]; ps[j] = 0.f; }
            }
        }
        float mn[4];
#pragma unroll
        for (int j = 0; j < 4; ++j) {
            const float rst = (m[j] > thr) ? thr : 0.f;
            float v = 0.5f * m[j] + s[j];
            v = v - rst;
            m[j] = v; mn[j] = v;
        }
#pragma unroll
        for (int j = 0; j < 4; ++j) {
            const unsigned long long mask = __ballot(mn[j] > thr);
            if (nl == 0) {
                const int br = 16 * wv + bq + 4 * j;
                spk1_bits[((size_t)t * BATCH + (b0 + br)) * 64 + blockIdx.x] =
                    (uint16_t)((mask >> (16 * bq)) & 0xFFFFull);
            }
        }
    }
}

// ---------------- K2a: output-layer currents for all t ---------------------
__global__ __launch_bounds__(256) void k2a_gemm(
    const uint16_t* __restrict__ spk1_bits,
    const float* __restrict__ W2,     // [20][1024]
    float* __restrict__ cur2)         // [100*256][20]
{
    const int gid = blockIdx.x * 256 + threadIdx.x;
    const int q = gid / OUT_DIM, n = gid % OUT_DIM;
    if (q >= T_STEPS * BATCH) return;

    const uint16_t* bits = spk1_bits + (size_t)q * 64;
    const float* w = W2 + (size_t)n * H_DIM;
    float s = 0.f, ps = 0.f;
    for (int wi = 0; wi < 64; ++wi) {
        const uint32_t bw = bits[wi];
        const float4* w4p = (const float4*)(w + wi * 16);
#pragma unroll
        for (int f = 0; f < 4; ++f) {
            const float4 w4 = w4p[f];
            const int base = f * 4;
            ps += ((bw >> (base + 0)) & 1u) ? w4.x : 0.0f;
            ps += ((bw >> (base + 1)) & 1u) ? w4.y : 0.0f;
            ps += ((bw >> (base + 2)) & 1u) ? w4.z : 0.0f;
            ps += ((bw >> (base + 3)) & 1u) ? w4.w : 0.0f;
        }
        if (wi == 31) { s += ps; ps = 0.f; }   // panel join at k=512
    }
    s += ps;                                    // final join at k=1024
    cur2[(size_t)q * OUT_DIM + n] = s;
}

// ---------------- K2b: output-layer LIF recurrence + final writes ----------
__global__ __launch_bounds__(256) void k2b_lif_out(
    const float* __restrict__ cur2,
    const float* __restrict__ thr_p,
    float* __restrict__ out)           // [spk: 100*256*20][mem: 100*256*20]
{
    const int idx = blockIdx.x * 256 + threadIdx.x;
    if (idx >= BATCH * OUT_DIM) return;
    const float thr = *thr_p;
    const size_t stride = (size_t)BATCH * OUT_DIM;
    float m = 0.f;
    for (int t = 0; t < T_STEPS; ++t) {
        const float cur = cur2[(size_t)t * stride + idx];
        const float rst = (m > thr) ? thr : 0.f;
        float v = 0.5f * m + cur;
        v = v - rst;
        m = v;
        out[(size_t)t * stride + idx] = (v > thr) ? 1.0f : 0.0f;
        out[(size_t)T_STEPS * stride + (size_t)t * stride + idx] = v;
    }
}

extern "C" void kernel_launch(void* const* d_in, const int* in_sizes, int n_in,
                              void* d_out, int out_size, void* d_ws, size_t ws_size,
                              hipStream_t stream)
{
    const float* x    = (const float*)d_in[0];
    const float* W0   = (const float*)d_in[1];
    const float* W1   = (const float*)d_in[2];
    const float* W2   = (const float*)d_in[3];
    const float* thr0 = (const float*)d_in[4];
    const float* thr1 = (const float*)d_in[5];
    const float* thr2 = (const float*)d_in[6];

    // ws layout (13.84 MB total, within verified >=14 MB):
    //   spk0_bits 3.277 MB | spk1_bits 3.277 MB | cur2 2.048 MB |
    //   cur0 4.194 MB | m0state 1.049 MB
    uint16_t* spk0_bits = (uint16_t*)d_ws;
    uint16_t* spk1_bits = spk0_bits + (size_t)T_STEPS * BATCH * 64;
    float*    cur2      = (float*)(spk1_bits + (size_t)T_STEPS * BATCH * 64);
    float*    cur0      = cur2 + (size_t)T_STEPS * BATCH * OUT_DIM;
    float*    m0state   = cur0 + (size_t)BATCH * TC * H_DIM;

    hipMemsetAsync(m0state, 0, (size_t)BATCH * H_DIM * sizeof(float), stream);

    for (int tc = 0; tc < NCHUNK; ++tc) {
        k0a_gemm<<<dim3(16, 16), 256, 0, stream>>>(x, W0, cur0, tc);
        lif0<<<dim3(4, BATCH), 256, 0, stream>>>(cur0, m0state, thr0, spk0_bits, tc);
    }
    k1_gemm_lif<<<dim3(H_DIM / 16, BATCH / 64), 256, 0, stream>>>(
        spk0_bits, W1, thr1, spk1_bits);
    k2a_gemm<<<(T_STEPS * BATCH * OUT_DIM) / 256, 256, 0, stream>>>(
        spk1_bits, W2, cur2);
    k2b_lif_out<<<(BATCH * OUT_DIM + 255) / 256, 256, 0, stream>>>(
        cur2, thr2, (float*)d_out);
}

// Round 25
// 3160.634 us; speedup vs baseline: 16.7391x; 1.3389x over previous
//
#include <hip/hip_runtime.h>
#include <hip/hip_bf16.h>
#include <stdint.h>

#define BATCH   256
#define T_STEPS 100
#define IN_DIM  700
#define H_DIM   1024
#define OUT_DIM 20
#define TC      4      // timesteps per chunk
#define NCHUNK  25     // 100 / TC

// Exactness contract (validated R21-R24): per output element, cur = serial
// ascending fmaf chain in k, straight 512-chunks, one f32 add per chunk join
// (first join exact from 0). LIF: rst=(m>thr)?thr:0; v=0.5f*m+cur; v-=rst;
// spk=(v>thr).  K=700 panels [512,188]; K=1024 panels [512,512].
//
// Both GEMMs: 64x64 tile, 256 thr, 4x4 regs/thread.
// Row mapping: tile row r = 4*ty + i  ->  b = by*16+ty, ti = i  (so each
// thread's 4 rows are the 4 timesteps of ONE batch row -> LIF in epilogue).

// ---------------- L0: x (f32) x W0 -> spk0 bits, fused LIF -----------------
__global__ __launch_bounds__(256) void gemm_lif_l0(
    const float* __restrict__ x,      // [256][100][700]
    const float* __restrict__ W0,     // [1024][700]
    const float* __restrict__ thr_p,
    float* __restrict__ mstate,       // [256*1024]
    uint16_t* __restrict__ spk_bits,  // [100][256][64]
    int tc)
{
    __shared__ __align__(16) float As[64][68];
    __shared__ __align__(16) float Ws[64][68];   // f4-slot swizzle: f4 ^ (r&7)

    const int tid = threadIdx.x;
    const int n0 = blockIdx.x * 64;
    const int by = blockIdx.y;
    const int tx = tid & 15, ty = tid >> 4;

    float ps[4][4], s[4][4];
#pragma unroll
    for (int i = 0; i < 4; ++i)
#pragma unroll
        for (int j = 0; j < 4; ++j) { ps[i][j] = 0.f; s[i][j] = 0.f; }

    const int sr = tid >> 2, q = tid & 3;        // staging: row, quarter
    const float* xsrc = x + ((size_t)(by * 16 + (sr >> 2)) * T_STEPS
                             + tc * TC + (sr & 3)) * IN_DIM;
    const float* wsrc = W0 + (size_t)(n0 + sr) * IN_DIM;

#pragma unroll 1
    for (int c = 0; c < 11; ++c) {               // 64-k chunks; joins c7, c10
        __syncthreads();
#pragma unroll
        for (int u = 0; u < 4; ++u) {
            const int f4 = q * 4 + u;
            const int k = c * 64 + f4 * 4;
            const float4 av = (k < IN_DIM) ? *(const float4*)(xsrc + k)
                                           : make_float4(0.f, 0.f, 0.f, 0.f);
            *(float4*)&As[sr][f4 * 4] = av;
            const float4 wv = (k < IN_DIM) ? *(const float4*)(wsrc + k)
                                           : make_float4(0.f, 0.f, 0.f, 0.f);
            *(float4*)&Ws[sr][(f4 ^ (sr & 7)) * 4] = wv;
        }
        __syncthreads();

        const int kmax4 = (c == 10) ? 15 : 16;
        const int wxor = tx & 7;
        for (int k4 = 0; k4 < kmax4; ++k4) {
            float4 av[4], wv[4];
#pragma unroll
            for (int i = 0; i < 4; ++i)
                av[i] = *(const float4*)&As[4 * ty + i][k4 * 4];
#pragma unroll
            for (int j = 0; j < 4; ++j)
                wv[j] = *(const float4*)&Ws[tx + 16 * j][(k4 ^ wxor) * 4];
#pragma unroll
            for (int i = 0; i < 4; ++i)
#pragma unroll
                for (int j = 0; j < 4; ++j) {
                    ps[i][j] = __builtin_fmaf(av[i].x, wv[j].x, ps[i][j]);
                    ps[i][j] = __builtin_fmaf(av[i].y, wv[j].y, ps[i][j]);
                    ps[i][j] = __builtin_fmaf(av[i].z, wv[j].z, ps[i][j]);
                    ps[i][j] = __builtin_fmaf(av[i].w, wv[j].w, ps[i][j]);
                }
        }
        if (c == 7 || c == 10) {                 // BLIS joins k=512, 700
#pragma unroll
            for (int i = 0; i < 4; ++i)
#pragma unroll
                for (int j = 0; j < 4; ++j) { s[i][j] += ps[i][j]; ps[i][j] = 0.f; }
        }
    }

    // fused LIF epilogue: b = by*16 + ty; t = tc*TC + i; n = n0 + tx + 16j
    const float thr = *thr_p;
    const int b = by * 16 + ty;
    float m[4];
#pragma unroll
    for (int j = 0; j < 4; ++j)
        m[j] = mstate[(size_t)b * H_DIM + n0 + tx + 16 * j];
#pragma unroll
    for (int i = 0; i < 4; ++i) {
#pragma unroll
        for (int j = 0; j < 4; ++j) {
            const float rst = (m[j] > thr) ? thr : 0.f;
            float v = 0.5f * m[j] + s[i][j];
            v = v - rst;
            m[j] = v;
        }
        const int t = tc * TC + i;
        const int g = ty & 3;                    // lane group in wave
#pragma unroll
        for (int j = 0; j < 4; ++j) {
            const unsigned long long mask = __ballot(m[j] > thr);
            if (tx == 0)
                spk_bits[((size_t)t * BATCH + b) * 64 + (n0 >> 4) + j] =
                    (uint16_t)((mask >> (16 * g)) & 0xFFFFull);
        }
    }
#pragma unroll
    for (int j = 0; j < 4; ++j)
        mstate[(size_t)b * H_DIM + n0 + tx + 16 * j] = m[j];
}

// ---------------- L1: spk0 bits x W1 -> spk1 bits, fused LIF ---------------
__global__ __launch_bounds__(256) void gemm_lif_l1(
    const uint16_t* __restrict__ spk0_bits,
    const float* __restrict__ W1,     // [1024][1024]
    const float* __restrict__ thr_p,
    float* __restrict__ mstate,       // [256*1024]
    uint16_t* __restrict__ spk_bits,  // [100][256][64]
    int tc)
{
    __shared__ __align__(16) float As[64][68];
    __shared__ __align__(16) float Ws[64][68];

    const int tid = threadIdx.x;
    const int n0 = blockIdx.x * 64;
    const int by = blockIdx.y;
    const int tx = tid & 15, ty = tid >> 4;

    float ps[4][4], s[4][4];
#pragma unroll
    for (int i = 0; i < 4; ++i)
#pragma unroll
        for (int j = 0; j < 4; ++j) { ps[i][j] = 0.f; s[i][j] = 0.f; }

    const int sr = tid >> 2, q = tid & 3;
    const uint16_t* bsrc = spk0_bits +
        ((size_t)(tc * TC + (sr & 3)) * BATCH + by * 16 + (sr >> 2)) * 64;
    const float* wsrc = W1 + (size_t)(n0 + sr) * H_DIM;

#pragma unroll 1
    for (int c = 0; c < 16; ++c) {               // 64-k chunks; joins c7, c15
        __syncthreads();
        {   // A from bits: word c*4+q covers k = c*64 + q*16 .. +15
            const uint32_t w = bsrc[c * 4 + q];
#pragma unroll
            for (int u = 0; u < 4; ++u) {
                float4 v;
                v.x = ((w >> (u * 4 + 0)) & 1u) ? 1.0f : 0.0f;
                v.y = ((w >> (u * 4 + 1)) & 1u) ? 1.0f : 0.0f;
                v.z = ((w >> (u * 4 + 2)) & 1u) ? 1.0f : 0.0f;
                v.w = ((w >> (u * 4 + 3)) & 1u) ? 1.0f : 0.0f;
                *(float4*)&As[sr][(q * 4 + u) * 4] = v;
            }
#pragma unroll
            for (int u = 0; u < 4; ++u) {
                const int f4 = q * 4 + u;
                const float4 wv = *(const float4*)(wsrc + c * 64 + f4 * 4);
                *(float4*)&Ws[sr][(f4 ^ (sr & 7)) * 4] = wv;
            }
        }
        __syncthreads();

        const int wxor = tx & 7;
        for (int k4 = 0; k4 < 16; ++k4) {
            float4 av[4], wv[4];
#pragma unroll
            for (int i = 0; i < 4; ++i)
                av[i] = *(const float4*)&As[4 * ty + i][k4 * 4];
#pragma unroll
            for (int j = 0; j < 4; ++j)
                wv[j] = *(const float4*)&Ws[tx + 16 * j][(k4 ^ wxor) * 4];
#pragma unroll
            for (int i = 0; i < 4; ++i)
#pragma unroll
                for (int j = 0; j < 4; ++j) {
                    ps[i][j] = __builtin_fmaf(av[i].x, wv[j].x, ps[i][j]);
                    ps[i][j] = __builtin_fmaf(av[i].y, wv[j].y, ps[i][j]);
                    ps[i][j] = __builtin_fmaf(av[i].z, wv[j].z, ps[i][j]);
                    ps[i][j] = __builtin_fmaf(av[i].w, wv[j].w, ps[i][j]);
                }
        }
        if (c == 7 || c == 15) {                 // BLIS joins k=512, 1024
#pragma unroll
            for (int i = 0; i < 4; ++i)
#pragma unroll
                for (int j = 0; j < 4; ++j) { s[i][j] += ps[i][j]; ps[i][j] = 0.f; }
        }
    }

    const float thr = *thr_p;
    const int b = by * 16 + ty;
    float m[4];
#pragma unroll
    for (int j = 0; j < 4; ++j)
        m[j] = mstate[(size_t)b * H_DIM + n0 + tx + 16 * j];
#pragma unroll
    for (int i = 0; i < 4; ++i) {
#pragma unroll
        for (int j = 0; j < 4; ++j) {
            const float rst = (m[j] > thr) ? thr : 0.f;
            float v = 0.5f * m[j] + s[i][j];
            v = v - rst;
            m[j] = v;
        }
        const int t = tc * TC + i;
        const int g = ty & 3;
#pragma unroll
        for (int j = 0; j < 4; ++j) {
            const unsigned long long mask = __ballot(m[j] > thr);
            if (tx == 0)
                spk_bits[((size_t)t * BATCH + b) * 64 + (n0 >> 4) + j] =
                    (uint16_t)((mask >> (16 * g)) & 0xFFFFull);
        }
    }
#pragma unroll
    for (int j = 0; j < 4; ++j)
        mstate[(size_t)b * H_DIM + n0 + tx + 16 * j] = m[j];
}

// ---------------- K2a: output-layer currents for all t ---------------------
__global__ __launch_bounds__(256) void k2a_gemm(
    const uint16_t* __restrict__ spk1_bits,
    const float* __restrict__ W2,     // [20][1024]
    float* __restrict__ cur2)         // [100*256][20]
{
    const int gid = blockIdx.x * 256 + threadIdx.x;
    const int q = gid / OUT_DIM, n = gid % OUT_DIM;
    if (q >= T_STEPS * BATCH) return;

    const uint16_t* bits = spk1_bits + (size_t)q * 64;
    const float* w = W2 + (size_t)n * H_DIM;
    float s = 0.f, ps = 0.f;
    for (int wi = 0; wi < 64; ++wi) {
        const uint32_t bw = bits[wi];
        const float4* w4p = (const float4*)(w + wi * 16);
#pragma unroll
        for (int f = 0; f < 4; ++f) {
            const float4 w4 = w4p[f];
            const int base = f * 4;
            ps += ((bw >> (base + 0)) & 1u) ? w4.x : 0.0f;
            ps += ((bw >> (base + 1)) & 1u) ? w4.y : 0.0f;
            ps += ((bw >> (base + 2)) & 1u) ? w4.z : 0.0f;
            ps += ((bw >> (base + 3)) & 1u) ? w4.w : 0.0f;
        }
        if (wi == 31) { s += ps; ps = 0.f; }   // panel join at k=512
    }
    s += ps;                                    // final join at k=1024
    cur2[(size_t)q * OUT_DIM + n] = s;
}

// ---------------- K2b: output-layer LIF recurrence + final writes ----------
__global__ __launch_bounds__(256) void k2b_lif_out(
    const float* __restrict__ cur2,
    const float* __restrict__ thr_p,
    float* __restrict__ out)           // [spk: 100*256*20][mem: 100*256*20]
{
    const int idx = blockIdx.x * 256 + threadIdx.x;
    if (idx >= BATCH * OUT_DIM) return;
    const float thr = *thr_p;
    const size_t stride = (size_t)BATCH * OUT_DIM;
    float m = 0.f;
    for (int t = 0; t < T_STEPS; ++t) {
        const float cur = cur2[(size_t)t * stride + idx];
        const float rst = (m > thr) ? thr : 0.f;
        float v = 0.5f * m + cur;
        v = v - rst;
        m = v;
        out[(size_t)t * stride + idx] = (v > thr) ? 1.0f : 0.0f;
        out[(size_t)T_STEPS * stride + (size_t)t * stride + idx] = v;
    }
}

extern "C" void kernel_launch(void* const* d_in, const int* in_sizes, int n_in,
                              void* d_out, int out_size, void* d_ws, size_t ws_size,
                              hipStream_t stream)
{
    const float* x    = (const float*)d_in[0];
    const float* W0   = (const float*)d_in[1];
    const float* W1   = (const float*)d_in[2];
    const float* W2   = (const float*)d_in[3];
    const float* thr0 = (const float*)d_in[4];
    const float* thr1 = (const float*)d_in[5];
    const float* thr2 = (const float*)d_in[6];

    // ws (10.7 MB): spk0 3.277 | spk1 3.277 | cur2 2.048 | m0 1.049 | m1 1.049
    uint16_t* spk0_bits = (uint16_t*)d_ws;
    uint16_t* spk1_bits = spk0_bits + (size_t)T_STEPS * BATCH * 64;
    float*    cur2      = (float*)(spk1_bits + (size_t)T_STEPS * BATCH * 64);
    float*    m0state   = cur2 + (size_t)T_STEPS * BATCH * OUT_DIM;
    float*    m1state   = m0state + (size_t)BATCH * H_DIM;

    hipMemsetAsync(m0state, 0, (size_t)BATCH * H_DIM * 2 * sizeof(float), stream);

    const dim3 grid(H_DIM / 64, BATCH / 16);   // (16, 16) = 256 blocks
    for (int tc = 0; tc < NCHUNK; ++tc)
        gemm_lif_l0<<<grid, 256, 0, stream>>>(x, W0, thr0, m0state, spk0_bits, tc);
    for (int tc = 0; tc < NCHUNK; ++tc)
        gemm_lif_l1<<<grid, 256, 0, stream>>>(spk0_bits, W1, thr1, m1state, spk1_bits, tc);
    k2a_gemm<<<(T_STEPS * BATCH * OUT_DIM) / 256, 256, 0, stream>>>(
        spk1_bits, W2, cur2);
    k2b_lif_out<<<(BATCH * OUT_DIM + 255) / 256, 256, 0, stream>>>(
        cur2, thr2, (float*)d_out);
}

// Round 26
// 2780.177 us; speedup vs baseline: 19.0298x; 1.1368x over previous
//
#include <hip/hip_runtime.h>
#include <hip/hip_bf16.h>
#include <stdint.h>

#define BATCH   256
#define T_STEPS 100
#define IN_DIM  700
#define H_DIM   1024
#define OUT_DIM 20
#define TC      4      // timesteps per chunk
#define NCHUNK  25     // 100 / TC

// Exactness contract (validated R21-R25): per output element, cur = serial
// ascending fmaf chain in k, straight 512-chunks, one f32 add per chunk join
// (first join exact from 0). LIF: rst=(m>thr)?thr:0; v=0.5f*m+cur; v-=rst;
// spk=(v>thr).  K=700 panels [512,188]; K=1024 panels [512,512].
// Skipping k where bit==0 is exact: fl(x+0)=x, no -0/NaN reachable.

__device__ __forceinline__ void lif_epilogue(
    const float s[4][4], const float* __restrict__ thr_p,
    float* __restrict__ mstate, uint16_t* __restrict__ spk_bits,
    int b, int n0, int tbase, int tx, int ty)
{
    const float thr = *thr_p;
    float m[4];
#pragma unroll
    for (int j = 0; j < 4; ++j)
        m[j] = mstate[(size_t)b * H_DIM + n0 + tx + 16 * j];
#pragma unroll
    for (int i = 0; i < 4; ++i) {
#pragma unroll
        for (int j = 0; j < 4; ++j) {
            const float rst = (m[j] > thr) ? thr : 0.f;
            float v = 0.5f * m[j] + s[i][j];
            v = v - rst;
            m[j] = v;
        }
        const int t = tbase + i;
        const int g = ty & 3;
#pragma unroll
        for (int j = 0; j < 4; ++j) {
            const unsigned long long mask = __ballot(m[j] > thr);
            if (tx == 0)
                spk_bits[((size_t)t * BATCH + b) * 64 + (n0 >> 4) + j] =
                    (uint16_t)((mask >> (16 * g)) & 0xFFFFull);
        }
    }
#pragma unroll
    for (int j = 0; j < 4; ++j)
        mstate[(size_t)b * H_DIM + n0 + tx + 16 * j] = m[j];
}

// ---- fused: blocks x<16 run L0 chunk tc; x>=16 run L1 chunk tc-1 ----------
// 64x64 tile, 256 thr, 4x4 regs/thread; tile row r = 4*ty+i -> (b=by*16+ty,
// ti=i) so each thread's 4 rows are 4 timesteps of one batch row.
__global__ __launch_bounds__(256) void fused_l0_l1(
    const float* __restrict__ x,       // [256][100][700]
    const float* __restrict__ W0,      // [1024][700]
    const float* __restrict__ W1,      // [1024][1024]
    const float* __restrict__ thr0_p,
    const float* __restrict__ thr1_p,
    float* __restrict__ m0state,
    float* __restrict__ m1state,
    uint16_t* __restrict__ spk0_bits,  // [100][256][64]
    uint16_t* __restrict__ spk1_bits,
    int tc)
{
    __shared__ __align__(16) float As[64][68];
    __shared__ __align__(16) float Ws[64][68];   // f4-slot swizzle: f4 ^ (r&7)

    const int tid = threadIdx.x;
    const int tx = tid & 15, ty = tid >> 4;
    const int by = blockIdx.y;
    const bool isL0 = (blockIdx.x < 16);
    const int n0 = (isL0 ? blockIdx.x : blockIdx.x - 16) * 64;
    const int myc = isL0 ? tc : tc - 1;          // this block's chunk index
    if (isL0 && myc >= NCHUNK) return;           // block-uniform exits
    if (!isL0 && myc < 0) return;

    float ps[4][4], s[4][4];
#pragma unroll
    for (int i = 0; i < 4; ++i)
#pragma unroll
        for (int j = 0; j < 4; ++j) { ps[i][j] = 0.f; s[i][j] = 0.f; }

    const int sr = tid >> 2, q = tid & 3;        // staging: row, quarter
    const int b = by * 16 + ty;
    const int wxor = tx & 7;

    if (isL0) {
        const float* xsrc = x + ((size_t)(by * 16 + (sr >> 2)) * T_STEPS
                                 + myc * TC + (sr & 3)) * IN_DIM;
        const float* wsrc = W0 + (size_t)(n0 + sr) * IN_DIM;
#pragma unroll 1
        for (int c = 0; c < 11; ++c) {           // joins c7 (512), c10 (700)
            __syncthreads();
#pragma unroll
            for (int u = 0; u < 4; ++u) {
                const int f4 = q * 4 + u;
                const int k = c * 64 + f4 * 4;
                const float4 av = (k < IN_DIM) ? *(const float4*)(xsrc + k)
                                               : make_float4(0.f, 0.f, 0.f, 0.f);
                *(float4*)&As[sr][f4 * 4] = av;
                const float4 wv = (k < IN_DIM) ? *(const float4*)(wsrc + k)
                                               : make_float4(0.f, 0.f, 0.f, 0.f);
                *(float4*)&Ws[sr][(f4 ^ (sr & 7)) * 4] = wv;
            }
            __syncthreads();
            const int kmax4 = (c == 10) ? 15 : 16;
            for (int k4 = 0; k4 < kmax4; ++k4) {
                float4 av[4], wv[4];
#pragma unroll
                for (int i = 0; i < 4; ++i)
                    av[i] = *(const float4*)&As[4 * ty + i][k4 * 4];
#pragma unroll
                for (int j = 0; j < 4; ++j)
                    wv[j] = *(const float4*)&Ws[tx + 16 * j][(k4 ^ wxor) * 4];
#pragma unroll
                for (int i = 0; i < 4; ++i)
#pragma unroll
                    for (int j = 0; j < 4; ++j) {
                        ps[i][j] = __builtin_fmaf(av[i].x, wv[j].x, ps[i][j]);
                        ps[i][j] = __builtin_fmaf(av[i].y, wv[j].y, ps[i][j]);
                        ps[i][j] = __builtin_fmaf(av[i].z, wv[j].z, ps[i][j]);
                        ps[i][j] = __builtin_fmaf(av[i].w, wv[j].w, ps[i][j]);
                    }
            }
            if (c == 7 || c == 10) {
#pragma unroll
                for (int i = 0; i < 4; ++i)
#pragma unroll
                    for (int j = 0; j < 4; ++j) { s[i][j] += ps[i][j]; ps[i][j] = 0.f; }
            }
        }
        lif_epilogue(s, thr0_p, m0state, spk0_bits, b, n0, myc * TC, tx, ty);
    } else {
        const uint16_t* bsrc = spk0_bits +
            ((size_t)(myc * TC + (sr & 3)) * BATCH + by * 16 + (sr >> 2)) * 64;
        const float* wsrc = W1 + (size_t)(n0 + sr) * H_DIM;
#pragma unroll 1
        for (int c = 0; c < 16; ++c) {           // joins c7 (512), c15 (1024)
            __syncthreads();
            {
                const uint32_t w = bsrc[c * 4 + q];
#pragma unroll
                for (int u = 0; u < 4; ++u) {
                    float4 v;
                    v.x = ((w >> (u * 4 + 0)) & 1u) ? 1.0f : 0.0f;
                    v.y = ((w >> (u * 4 + 1)) & 1u) ? 1.0f : 0.0f;
                    v.z = ((w >> (u * 4 + 2)) & 1u) ? 1.0f : 0.0f;
                    v.w = ((w >> (u * 4 + 3)) & 1u) ? 1.0f : 0.0f;
                    *(float4*)&As[sr][(q * 4 + u) * 4] = v;
                }
#pragma unroll
                for (int u = 0; u < 4; ++u) {
                    const int f4 = q * 4 + u;
                    const float4 wv = *(const float4*)(wsrc + c * 64 + f4 * 4);
                    *(float4*)&Ws[sr][(f4 ^ (sr & 7)) * 4] = wv;
                }
            }
            __syncthreads();
            for (int k4 = 0; k4 < 16; ++k4) {
                float4 av[4], wv[4];
#pragma unroll
                for (int i = 0; i < 4; ++i)
                    av[i] = *(const float4*)&As[4 * ty + i][k4 * 4];
#pragma unroll
                for (int j = 0; j < 4; ++j)
                    wv[j] = *(const float4*)&Ws[tx + 16 * j][(k4 ^ wxor) * 4];
#pragma unroll
                for (int i = 0; i < 4; ++i)
#pragma unroll
                    for (int j = 0; j < 4; ++j) {
                        ps[i][j] = __builtin_fmaf(av[i].x, wv[j].x, ps[i][j]);
                        ps[i][j] = __builtin_fmaf(av[i].y, wv[j].y, ps[i][j]);
                        ps[i][j] = __builtin_fmaf(av[i].z, wv[j].z, ps[i][j]);
                        ps[i][j] = __builtin_fmaf(av[i].w, wv[j].w, ps[i][j]);
                    }
            }
            if (c == 7 || c == 15) {
#pragma unroll
                for (int i = 0; i < 4; ++i)
#pragma unroll
                    for (int j = 0; j < 4; ++j) { s[i][j] += ps[i][j]; ps[i][j] = 0.f; }
            }
        }
        lif_epilogue(s, thr1_p, m1state, spk1_bits, b, n0, myc * TC, tx, ty);
    }
}

// ---------------- K2a: output currents; 4 independent chains/thread --------
__global__ __launch_bounds__(256) void k2a_gemm(
    const uint16_t* __restrict__ spk1_bits,
    const float* __restrict__ W2,     // [20][1024]
    float* __restrict__ cur2)         // [100*256][20]
{
    const int gid = blockIdx.x * 256 + threadIdx.x;   // 500 blocks
    const int q = gid / 5;
    const int n0 = (gid % 5) * 4;
    if (q >= T_STEPS * BATCH) return;

    const uint16_t* bits = spk1_bits + (size_t)q * 64;
    const float* wr0 = W2 + (size_t)(n0 + 0) * H_DIM;
    const float* wr1 = W2 + (size_t)(n0 + 1) * H_DIM;
    const float* wr2 = W2 + (size_t)(n0 + 2) * H_DIM;
    const float* wr3 = W2 + (size_t)(n0 + 3) * H_DIM;

    float ps[4] = {0.f, 0.f, 0.f, 0.f}, s[4] = {0.f, 0.f, 0.f, 0.f};
    for (int wi = 0; wi < 64; ++wi) {
        const uint32_t bw = bits[wi];
        const int kb = wi * 16;
#pragma unroll
        for (int f = 0; f < 4; ++f) {
            const float4 a = *(const float4*)(wr0 + kb + f * 4);
            const float4 bq = *(const float4*)(wr1 + kb + f * 4);
            const float4 cq = *(const float4*)(wr2 + kb + f * 4);
            const float4 dq = *(const float4*)(wr3 + kb + f * 4);
            const int base = f * 4;
            ps[0] += ((bw >> (base + 0)) & 1u) ? a.x : 0.f;
            ps[1] += ((bw >> (base + 0)) & 1u) ? bq.x : 0.f;
            ps[2] += ((bw >> (base + 0)) & 1u) ? cq.x : 0.f;
            ps[3] += ((bw >> (base + 0)) & 1u) ? dq.x : 0.f;
            ps[0] += ((bw >> (base + 1)) & 1u) ? a.y : 0.f;
            ps[1] += ((bw >> (base + 1)) & 1u) ? bq.y : 0.f;
            ps[2] += ((bw >> (base + 1)) & 1u) ? cq.y : 0.f;
            ps[3] += ((bw >> (base + 1)) & 1u) ? dq.y : 0.f;
            ps[0] += ((bw >> (base + 2)) & 1u) ? a.z : 0.f;
            ps[1] += ((bw >> (base + 2)) & 1u) ? bq.z : 0.f;
            ps[2] += ((bw >> (base + 2)) & 1u) ? cq.z : 0.f;
            ps[3] += ((bw >> (base + 2)) & 1u) ? dq.z : 0.f;
            ps[0] += ((bw >> (base + 3)) & 1u) ? a.w : 0.f;
            ps[1] += ((bw >> (base + 3)) & 1u) ? bq.w : 0.f;
            ps[2] += ((bw >> (base + 3)) & 1u) ? cq.w : 0.f;
            ps[3] += ((bw >> (base + 3)) & 1u) ? dq.w : 0.f;
        }
        if (wi == 31) {                          // panel join at k=512
#pragma unroll
            for (int j = 0; j < 4; ++j) { s[j] += ps[j]; ps[j] = 0.f; }
        }
    }
#pragma unroll
    for (int j = 0; j < 4; ++j) s[j] += ps[j];   // final join at k=1024
#pragma unroll
    for (int j = 0; j < 4; ++j)
        cur2[(size_t)q * OUT_DIM + n0 + j] = s[j];
}

// ---------------- K2b: output-layer LIF recurrence + final writes ----------
__global__ __launch_bounds__(256) void k2b_lif_out(
    const float* __restrict__ cur2,
    const float* __restrict__ thr_p,
    float* __restrict__ out)           // [spk: 100*256*20][mem: 100*256*20]
{
    const int idx = blockIdx.x * 256 + threadIdx.x;
    if (idx >= BATCH * OUT_DIM) return;
    const float thr = *thr_p;
    const size_t stride = (size_t)BATCH * OUT_DIM;
    float m = 0.f;
    for (int t = 0; t < T_STEPS; ++t) {
        const float cur = cur2[(size_t)t * stride + idx];
        const float rst = (m > thr) ? thr : 0.f;
        float v = 0.5f * m + cur;
        v = v - rst;
        m = v;
        out[(size_t)t * stride + idx] = (v > thr) ? 1.0f : 0.0f;
        out[(size_t)T_STEPS * stride + (size_t)t * stride + idx] = v;
    }
}

extern "C" void kernel_launch(void* const* d_in, const int* in_sizes, int n_in,
                              void* d_out, int out_size, void* d_ws, size_t ws_size,
                              hipStream_t stream)
{
    const float* x    = (const float*)d_in[0];
    const float* W0   = (const float*)d_in[1];
    const float* W1   = (const float*)d_in[2];
    const float* W2   = (const float*)d_in[3];
    const float* thr0 = (const float*)d_in[4];
    const float* thr1 = (const float*)d_in[5];
    const float* thr2 = (const float*)d_in[6];

    // ws (10.7 MB): spk0 3.277 | spk1 3.277 | cur2 2.048 | m0 1.049 | m1 1.049
    uint16_t* spk0_bits = (uint16_t*)d_ws;
    uint16_t* spk1_bits = spk0_bits + (size_t)T_STEPS * BATCH * 64;
    float*    cur2      = (float*)(spk1_bits + (size_t)T_STEPS * BATCH * 64);
    float*    m0state   = cur2 + (size_t)T_STEPS * BATCH * OUT_DIM;
    float*    m1state   = m0state + (size_t)BATCH * H_DIM;

    hipMemsetAsync(m0state, 0, (size_t)BATCH * H_DIM * 2 * sizeof(float), stream);

    const dim3 grid(32, 16);                     // 512 blocks: L0 | L1 pipelined
    for (int tc = 0; tc <= NCHUNK; ++tc)
        fused_l0_l1<<<grid, 256, 0, stream>>>(
            x, W0, W1, thr0, thr1, m0state, m1state, spk0_bits, spk1_bits, tc);

    k2a_gemm<<<500, 256, 0, stream>>>(spk1_bits, W2, cur2);
    k2b_lif_out<<<(BATCH * OUT_DIM + 255) / 256, 256, 0, stream>>>(
        cur2, thr2, (float*)d_out);
}

// Round 27
// 2611.370 us; speedup vs baseline: 20.2599x; 1.0646x over previous
//
#include <hip/hip_runtime.h>
#include <hip/hip_bf16.h>
#include <stdint.h>

#define BATCH   256
#define T_STEPS 100
#define IN_DIM  700
#define H_DIM   1024
#define OUT_DIM 20
#define TC      8      // timesteps per chunk
#define NCHUNK  13     // ceil(100/8); chunk 12 covers t=96..99 (+4 guarded)

// Exactness contract (validated R21-R26): per output element, cur = serial
// ascending fmaf chain in k, straight 512-chunks, one f32 add per chunk join
// (first join exact from 0). LIF: rst=(m>thr)?thr:0; v=0.5f*m+cur; v-=rst;
// spk=(v>thr).  K=700 panels [512,188]; K=1024 panels [512,512].
// Skipping k where bit==0 is exact: fl(x+0)=x, no -0/NaN reachable.

// Epilogue for TC=8: tile row r=4ty+i -> b=8by+(ty>>1), ti=(ty&1)*4+i.
// Even ty runs steps 0-3, passes m via shuffle to odd ty (steps 4-7).
__device__ __forceinline__ void lif_epilogue8(
    const float s[4][4], float thr,
    float* __restrict__ mstate, uint16_t* __restrict__ spk_bits,
    int b, int n0, int tbase, int tx, int ty, int ln)
{
    const int half = ty & 1;
    const int g = ty & 3;
    float m[4];
#pragma unroll
    for (int j = 0; j < 4; ++j)
        m[j] = mstate[(size_t)b * H_DIM + n0 + tx + 16 * j];
    // phase A: steps tbase..tbase+3 (even-ty lanes' results are the real ones)
#pragma unroll
    for (int i = 0; i < 4; ++i) {
#pragma unroll
        for (int j = 0; j < 4; ++j) {
            const float rst = (m[j] > thr) ? thr : 0.f;
            float v = 0.5f * m[j] + s[i][j];
            v = v - rst; m[j] = v;
        }
        const int t = tbase + i;
#pragma unroll
        for (int j = 0; j < 4; ++j) {
            const unsigned long long mask = __ballot(m[j] > thr);
            if (tx == 0 && half == 0 && t < T_STEPS)
                spk_bits[((size_t)t * BATCH + b) * 64 + (n0 >> 4) + j] =
                    (uint16_t)((mask >> (16 * g)) & 0xFFFFull);
        }
    }
    // hand m (post step tbase+3) from even lane to its odd partner (ln-16)
#pragma unroll
    for (int j = 0; j < 4; ++j)
        m[j] = __shfl(m[j], half ? (ln - 16) : ln);
    // phase B: steps tbase+4..tbase+7 (odd-ty lanes' results are real)
#pragma unroll
    for (int i = 0; i < 4; ++i) {
#pragma unroll
        for (int j = 0; j < 4; ++j) {
            const float rst = (m[j] > thr) ? thr : 0.f;
            float v = 0.5f * m[j] + s[i][j];
            v = v - rst; m[j] = v;
        }
        const int t = tbase + 4 + i;
#pragma unroll
        for (int j = 0; j < 4; ++j) {
            const unsigned long long mask = __ballot(m[j] > thr);
            if (tx == 0 && half == 1 && t < T_STEPS)
                spk_bits[((size_t)t * BATCH + b) * 64 + (n0 >> 4) + j] =
                    (uint16_t)((mask >> (16 * g)) & 0xFFFFull);
        }
    }
    if (half == 1) {
#pragma unroll
        for (int j = 0; j < 4; ++j)
            mstate[(size_t)b * H_DIM + n0 + tx + 16 * j] = m[j];
    }
}

// ---- fused: blocks x<16 run L0 chunk tc; x>=16 run L1 chunk tc-1 ----------
// 64x64 tile, 256 thr, 4x4 regs/thread. Grid (32, 32): 2048 rows = 256b x 8t.
__global__ __launch_bounds__(256, 4) void fused_l0_l1(
    const float* __restrict__ x,       // [256][100][700]
    const float* __restrict__ W0,      // [1024][700]
    const float* __restrict__ W1,      // [1024][1024]
    const float* __restrict__ thr0_p,
    const float* __restrict__ thr1_p,
    float* __restrict__ m0state,
    float* __restrict__ m1state,
    uint16_t* __restrict__ spk0_bits,  // [100][256][64]
    uint16_t* __restrict__ spk1_bits,
    int tc)
{
    __shared__ __align__(16) float As[64][68];
    __shared__ __align__(16) float Ws[64][68];   // f4-slot swizzle: f4 ^ (r&7)

    const int tid = threadIdx.x;
    const int tx = tid & 15, ty = tid >> 4, ln = tid & 63;
    const int by = blockIdx.y;
    const bool isL0 = (blockIdx.x < 16);
    const int n0 = (isL0 ? blockIdx.x : blockIdx.x - 16) * 64;
    const int myc = isL0 ? tc : tc - 1;
    if (isL0 && myc >= NCHUNK) return;           // block-uniform exits
    if (!isL0 && myc < 0) return;

    float ps[4][4], s[4][4];
#pragma unroll
    for (int i = 0; i < 4; ++i)
#pragma unroll
        for (int j = 0; j < 4; ++j) { ps[i][j] = 0.f; s[i][j] = 0.f; }

    const int sr = tid >> 2, q4 = tid & 3;       // staging: row, quarter
    const int b_s = 8 * by + (sr >> 3);
    int t_s = myc * TC + (sr & 7);
    if (t_s > T_STEPS - 1) t_s = T_STEPS - 1;    // tail clamp (results discarded)
    const int b = 8 * by + (ty >> 1);
    const int wxor = tx & 7;

    if (isL0) {
        const float* xsrc = x + ((size_t)b_s * T_STEPS + t_s) * IN_DIM;
        const float* wsrc = W0 + (size_t)(n0 + sr) * IN_DIM;
#pragma unroll 1
        for (int c = 0; c < 11; ++c) {           // joins c7 (512), c10 (700)
            __syncthreads();
#pragma unroll
            for (int u = 0; u < 4; ++u) {
                const int f4 = q4 * 4 + u;
                const int k = c * 64 + f4 * 4;
                const float4 av = (k < IN_DIM) ? *(const float4*)(xsrc + k)
                                               : make_float4(0.f, 0.f, 0.f, 0.f);
                *(float4*)&As[sr][f4 * 4] = av;
                const float4 wv = (k < IN_DIM) ? *(const float4*)(wsrc + k)
                                               : make_float4(0.f, 0.f, 0.f, 0.f);
                *(float4*)&Ws[sr][(f4 ^ (sr & 7)) * 4] = wv;
            }
            __syncthreads();
            const int kmax4 = (c == 10) ? 15 : 16;
            for (int k4 = 0; k4 < kmax4; ++k4) {
                float4 av[4], wv[4];
#pragma unroll
                for (int i = 0; i < 4; ++i)
                    av[i] = *(const float4*)&As[4 * ty + i][k4 * 4];
#pragma unroll
                for (int j = 0; j < 4; ++j)
                    wv[j] = *(const float4*)&Ws[tx + 16 * j][(k4 ^ wxor) * 4];
#pragma unroll
                for (int i = 0; i < 4; ++i)
#pragma unroll
                    for (int j = 0; j < 4; ++j) {
                        ps[i][j] = __builtin_fmaf(av[i].x, wv[j].x, ps[i][j]);
                        ps[i][j] = __builtin_fmaf(av[i].y, wv[j].y, ps[i][j]);
                        ps[i][j] = __builtin_fmaf(av[i].z, wv[j].z, ps[i][j]);
                        ps[i][j] = __builtin_fmaf(av[i].w, wv[j].w, ps[i][j]);
                    }
            }
            if (c == 7 || c == 10) {
#pragma unroll
                for (int i = 0; i < 4; ++i)
#pragma unroll
                    for (int j = 0; j < 4; ++j) { s[i][j] += ps[i][j]; ps[i][j] = 0.f; }
            }
        }
        lif_epilogue8(s, *thr0_p, m0state, spk0_bits, b, n0, myc * TC, tx, ty, ln);
    } else {
        const uint16_t* bsrc = spk0_bits + ((size_t)t_s * BATCH + b_s) * 64;
        const float* wsrc = W1 + (size_t)(n0 + sr) * H_DIM;
#pragma unroll 1
        for (int c = 0; c < 16; ++c) {           // joins c7 (512), c15 (1024)
            __syncthreads();
            {
                const uint32_t w = bsrc[c * 4 + q4];
#pragma unroll
                for (int u = 0; u < 4; ++u) {
                    float4 v;
                    v.x = ((w >> (u * 4 + 0)) & 1u) ? 1.0f : 0.0f;
                    v.y = ((w >> (u * 4 + 1)) & 1u) ? 1.0f : 0.0f;
                    v.z = ((w >> (u * 4 + 2)) & 1u) ? 1.0f : 0.0f;
                    v.w = ((w >> (u * 4 + 3)) & 1u) ? 1.0f : 0.0f;
                    *(float4*)&As[sr][(q4 * 4 + u) * 4] = v;
                }
#pragma unroll
                for (int u = 0; u < 4; ++u) {
                    const int f4 = q4 * 4 + u;
                    const float4 wv = *(const float4*)(wsrc + c * 64 + f4 * 4);
                    *(float4*)&Ws[sr][(f4 ^ (sr & 7)) * 4] = wv;
                }
            }
            __syncthreads();
            for (int k4 = 0; k4 < 16; ++k4) {
                float4 av[4], wv[4];
#pragma unroll
                for (int i = 0; i < 4; ++i)
                    av[i] = *(const float4*)&As[4 * ty + i][k4 * 4];
#pragma unroll
                for (int j = 0; j < 4; ++j)
                    wv[j] = *(const float4*)&Ws[tx + 16 * j][(k4 ^ wxor) * 4];
#pragma unroll
                for (int i = 0; i < 4; ++i)
#pragma unroll
                    for (int j = 0; j < 4; ++j) {
                        ps[i][j] = __builtin_fmaf(av[i].x, wv[j].x, ps[i][j]);
                        ps[i][j] = __builtin_fmaf(av[i].y, wv[j].y, ps[i][j]);
                        ps[i][j] = __builtin_fmaf(av[i].z, wv[j].z, ps[i][j]);
                        ps[i][j] = __builtin_fmaf(av[i].w, wv[j].w, ps[i][j]);
                    }
            }
            if (c == 7 || c == 15) {
#pragma unroll
                for (int i = 0; i < 4; ++i)
#pragma unroll
                    for (int j = 0; j < 4; ++j) { s[i][j] += ps[i][j]; ps[i][j] = 0.f; }
            }
        }
        lif_epilogue8(s, *thr1_p, m1state, spk1_bits, b, n0, myc * TC, tx, ty, ln);
    }
}

// ---- K2a: output currents; thread = (q, n-quad, half-chain) ---------------
// Exact: half-chains are the BLIS panels; k2b joins them (s = fl(h0+h1)).
// Group-major gid -> each block's W2 working set is 8 KB (L1-resident).
__global__ __launch_bounds__(256) void k2a_gemm(
    const uint16_t* __restrict__ spk1_bits,
    const float* __restrict__ W2,     // [20][1024]
    float* __restrict__ cur2h)        // [2][25600][20]
{
    const int gid = blockIdx.x * 256 + threadIdx.x;   // 1000 blocks = 256000
    const int grp = gid / 25600;       // 0..9
    const int q   = gid % 25600;
    const int nq  = grp >> 1;          // n-quad 0..4
    const int h   = grp & 1;           // half-chain

    const uint16_t* bits = spk1_bits + (size_t)q * 64 + h * 32;
    const float* wr0 = W2 + (size_t)(nq * 4 + 0) * H_DIM + h * 512;
    const float* wr1 = W2 + (size_t)(nq * 4 + 1) * H_DIM + h * 512;
    const float* wr2 = W2 + (size_t)(nq * 4 + 2) * H_DIM + h * 512;
    const float* wr3 = W2 + (size_t)(nq * 4 + 3) * H_DIM + h * 512;

    float ps[4] = {0.f, 0.f, 0.f, 0.f};
    for (int wi = 0; wi < 32; ++wi) {
        const uint32_t bw = bits[wi];
        const int kb = wi * 16;
#pragma unroll
        for (int f = 0; f < 4; ++f) {
            const float4 a = *(const float4*)(wr0 + kb + f * 4);
            const float4 bq = *(const float4*)(wr1 + kb + f * 4);
            const float4 cq = *(const float4*)(wr2 + kb + f * 4);
            const float4 dq = *(const float4*)(wr3 + kb + f * 4);
            const int base = f * 4;
            ps[0] += ((bw >> (base + 0)) & 1u) ? a.x : 0.f;
            ps[1] += ((bw >> (base + 0)) & 1u) ? bq.x : 0.f;
            ps[2] += ((bw >> (base + 0)) & 1u) ? cq.x : 0.f;
            ps[3] += ((bw >> (base + 0)) & 1u) ? dq.x : 0.f;
            ps[0] += ((bw >> (base + 1)) & 1u) ? a.y : 0.f;
            ps[1] += ((bw >> (base + 1)) & 1u) ? bq.y : 0.f;
            ps[2] += ((bw >> (base + 1)) & 1u) ? cq.y : 0.f;
            ps[3] += ((bw >> (base + 1)) & 1u) ? dq.y : 0.f;
            ps[0] += ((bw >> (base + 2)) & 1u) ? a.z : 0.f;
            ps[1] += ((bw >> (base + 2)) & 1u) ? bq.z : 0.f;
            ps[2] += ((bw >> (base + 2)) & 1u) ? cq.z : 0.f;
            ps[3] += ((bw >> (base + 2)) & 1u) ? dq.z : 0.f;
            ps[0] += ((bw >> (base + 3)) & 1u) ? a.w : 0.f;
            ps[1] += ((bw >> (base + 3)) & 1u) ? bq.w : 0.f;
            ps[2] += ((bw >> (base + 3)) & 1u) ? cq.w : 0.f;
            ps[3] += ((bw >> (base + 3)) & 1u) ? dq.w : 0.f;
        }
    }
    float* dst = cur2h + ((size_t)h * 25600 + q) * OUT_DIM + nq * 4;
#pragma unroll
    for (int j = 0; j < 4; ++j) dst[j] = ps[j];
}

// ---- K2b: join halves (exact panel join) + LIF recurrence + final writes --
__global__ __launch_bounds__(256) void k2b_lif_out(
    const float* __restrict__ cur2h,   // [2][25600][20]
    const float* __restrict__ thr_p,
    float* __restrict__ out)           // [spk: 100*256*20][mem: 100*256*20]
{
    const int idx = blockIdx.x * 256 + threadIdx.x;
    if (idx >= BATCH * OUT_DIM) return;
    const float thr = *thr_p;
    const size_t stride = (size_t)BATCH * OUT_DIM;
    float m = 0.f;
    for (int t = 0; t < T_STEPS; ++t) {
        const float h0 = cur2h[(size_t)t * stride + idx];
        const float h1 = cur2h[(size_t)25600 * OUT_DIM + (size_t)t * stride + idx];
        const float cur = h0 + h1;             // BLIS join at k=512
        const float rst = (m > thr) ? thr : 0.f;
        float v = 0.5f * m + cur;
        v = v - rst;
        m = v;
        out[(size_t)t * stride + idx] = (v > thr) ? 1.0f : 0.0f;
        out[(size_t)T_STEPS * stride + (size_t)t * stride + idx] = v;
    }
}

extern "C" void kernel_launch(void* const* d_in, const int* in_sizes, int n_in,
                              void* d_out, int out_size, void* d_ws, size_t ws_size,
                              hipStream_t stream)
{
    const float* x    = (const float*)d_in[0];
    const float* W0   = (const float*)d_in[1];
    const float* W1   = (const float*)d_in[2];
    const float* W2   = (const float*)d_in[3];
    const float* thr0 = (const float*)d_in[4];
    const float* thr1 = (const float*)d_in[5];
    const float* thr2 = (const float*)d_in[6];

    // ws (12.75 MB): spk0 3.277 | spk1 3.277 | cur2h 4.096 | m0 1.049 | m1 1.049
    uint16_t* spk0_bits = (uint16_t*)d_ws;
    uint16_t* spk1_bits = spk0_bits + (size_t)T_STEPS * BATCH * 64;
    float*    cur2h     = (float*)(spk1_bits + (size_t)T_STEPS * BATCH * 64);
    float*    m0state   = cur2h + (size_t)2 * 25600 * OUT_DIM;
    float*    m1state   = m0state + (size_t)BATCH * H_DIM;

    hipMemsetAsync(m0state, 0, (size_t)BATCH * H_DIM * 2 * sizeof(float), stream);

    const dim3 grid(32, 32);                     // 1024 blocks: L0 | L1 pipelined
    for (int tc = 0; tc <= NCHUNK; ++tc)
        fused_l0_l1<<<grid, 256, 0, stream>>>(
            x, W0, W1, thr0, thr1, m0state, m1state, spk0_bits, spk1_bits, tc);

    k2a_gemm<<<1000, 256, 0, stream>>>(spk1_bits, W2, cur2h);
    k2b_lif_out<<<(BATCH * OUT_DIM + 255) / 256, 256, 0, stream>>>(
        cur2h, thr2, (float*)d_out);
}

// Round 28
// 1798.776 us; speedup vs baseline: 29.4123x; 1.4517x over previous
//
#include <hip/hip_runtime.h>
#include <hip/hip_bf16.h>
#include <stdint.h>

#define BATCH   256
#define T_STEPS 100
#define IN_DIM  700
#define H_DIM   1024
#define OUT_DIM 20
#define TC      8      // timesteps per chunk
#define NCHUNK  13     // ceil(100/8); chunk 12 covers t=96..99 (+4 guarded)

// Exactness contract (validated R21-R27): per output element, cur = serial
// ascending fmaf chain in k, straight 512-chunks, one f32 add per chunk join
// (first join exact from 0). LIF: rst=(m>thr)?thr:0; v=0.5f*m+cur; v-=rst;
// spk=(v>thr).  K=700 panels [512,188]; K=1024 panels [512,512].
// Skipping k where bit==0 is exact: fl(x+0)=x, no -0/NaN reachable.
//
// LDS layout note (R28): [64][68] padding alone is conflict-free —
// row stride 272 B == 16 mod 128, so W-reads hit bank-quad (tx+k4)%8 (a
// permutation in tx, 2 lanes/quad = wave64 minimum) and staged writes land
// 2 lanes/quad. The former XOR swizzle BROKE this (non-permutation groups,
// 5.46e7 conflict cycles/dispatch) — removed.

// Epilogue for TC=8: tile row r=4ty+i -> b=8by+(ty>>1), ti=(ty&1)*4+i.
// Even ty runs steps 0-3, passes m via shuffle to odd ty (steps 4-7).
__device__ __forceinline__ void lif_epilogue8(
    const float s[4][4], float thr,
    float* __restrict__ mstate, uint16_t* __restrict__ spk_bits,
    int b, int n0, int tbase, int tx, int ty, int ln)
{
    const int half = ty & 1;
    const int g = ty & 3;
    float m[4];
#pragma unroll
    for (int j = 0; j < 4; ++j)
        m[j] = mstate[(size_t)b * H_DIM + n0 + tx + 16 * j];
    // phase A: steps tbase..tbase+3 (even-ty lanes' results are the real ones)
#pragma unroll
    for (int i = 0; i < 4; ++i) {
#pragma unroll
        for (int j = 0; j < 4; ++j) {
            const float rst = (m[j] > thr) ? thr : 0.f;
            float v = 0.5f * m[j] + s[i][j];
            v = v - rst; m[j] = v;
        }
        const int t = tbase + i;
#pragma unroll
        for (int j = 0; j < 4; ++j) {
            const unsigned long long mask = __ballot(m[j] > thr);
            if (tx == 0 && half == 0 && t < T_STEPS)
                spk_bits[((size_t)t * BATCH + b) * 64 + (n0 >> 4) + j] =
                    (uint16_t)((mask >> (16 * g)) & 0xFFFFull);
        }
    }
    // hand m (post step tbase+3) from even lane to its odd partner (ln-16)
#pragma unroll
    for (int j = 0; j < 4; ++j)
        m[j] = __shfl(m[j], half ? (ln - 16) : ln);
    // phase B: steps tbase+4..tbase+7 (odd-ty lanes' results are real)
#pragma unroll
    for (int i = 0; i < 4; ++i) {
#pragma unroll
        for (int j = 0; j < 4; ++j) {
            const float rst = (m[j] > thr) ? thr : 0.f;
            float v = 0.5f * m[j] + s[i][j];
            v = v - rst; m[j] = v;
        }
        const int t = tbase + 4 + i;
#pragma unroll
        for (int j = 0; j < 4; ++j) {
            const unsigned long long mask = __ballot(m[j] > thr);
            if (tx == 0 && half == 1 && t < T_STEPS)
                spk_bits[((size_t)t * BATCH + b) * 64 + (n0 >> 4) + j] =
                    (uint16_t)((mask >> (16 * g)) & 0xFFFFull);
        }
    }
    if (half == 1) {
#pragma unroll
        for (int j = 0; j < 4; ++j)
            mstate[(size_t)b * H_DIM + n0 + tx + 16 * j] = m[j];
    }
}

// ---- fused: blocks x<16 run L0 chunk tc; x>=16 run L1 chunk tc-1 ----------
// 64x64 tile, 256 thr, 4x4 regs/thread. Grid (32, 32): 2048 rows = 256b x 8t.
__global__ __launch_bounds__(256, 4) void fused_l0_l1(
    const float* __restrict__ x,       // [256][100][700]
    const float* __restrict__ W0,      // [1024][700]
    const float* __restrict__ W1,      // [1024][1024]
    const float* __restrict__ thr0_p,
    const float* __restrict__ thr1_p,
    float* __restrict__ m0state,
    float* __restrict__ m1state,
    uint16_t* __restrict__ spk0_bits,  // [100][256][64]
    uint16_t* __restrict__ spk1_bits,
    int tc)
{
    __shared__ __align__(16) float As[64][68];
    __shared__ __align__(16) float Ws[64][68];   // linear; padding = conflict-free

    const int tid = threadIdx.x;
    const int tx = tid & 15, ty = tid >> 4, ln = tid & 63;
    const int by = blockIdx.y;
    const bool isL0 = (blockIdx.x < 16);
    const int n0 = (isL0 ? blockIdx.x : blockIdx.x - 16) * 64;
    const int myc = isL0 ? tc : tc - 1;
    if (isL0 && myc >= NCHUNK) return;           // block-uniform exits
    if (!isL0 && myc < 0) return;

    float ps[4][4], s[4][4];
#pragma unroll
    for (int i = 0; i < 4; ++i)
#pragma unroll
        for (int j = 0; j < 4; ++j) { ps[i][j] = 0.f; s[i][j] = 0.f; }

    const int sr = tid >> 2, q4 = tid & 3;       // staging: row, quarter
    const int b_s = 8 * by + (sr >> 3);
    int t_s = myc * TC + (sr & 7);
    if (t_s > T_STEPS - 1) t_s = T_STEPS - 1;    // tail clamp (results discarded)
    const int b = 8 * by + (ty >> 1);

    if (isL0) {
        const float* xsrc = x + ((size_t)b_s * T_STEPS + t_s) * IN_DIM;
        const float* wsrc = W0 + (size_t)(n0 + sr) * IN_DIM;
#pragma unroll 1
        for (int c = 0; c < 11; ++c) {           // joins c7 (512), c10 (700)
            __syncthreads();
#pragma unroll
            for (int u = 0; u < 4; ++u) {
                const int f4 = q4 * 4 + u;
                const int k = c * 64 + f4 * 4;
                const float4 av = (k < IN_DIM) ? *(const float4*)(xsrc + k)
                                               : make_float4(0.f, 0.f, 0.f, 0.f);
                *(float4*)&As[sr][f4 * 4] = av;
                const float4 wv = (k < IN_DIM) ? *(const float4*)(wsrc + k)
                                               : make_float4(0.f, 0.f, 0.f, 0.f);
                *(float4*)&Ws[sr][f4 * 4] = wv;
            }
            __syncthreads();
            const int kmax4 = (c == 10) ? 15 : 16;
            for (int k4 = 0; k4 < kmax4; ++k4) {
                float4 av[4], wv[4];
#pragma unroll
                for (int i = 0; i < 4; ++i)
                    av[i] = *(const float4*)&As[4 * ty + i][k4 * 4];
#pragma unroll
                for (int j = 0; j < 4; ++j)
                    wv[j] = *(const float4*)&Ws[tx + 16 * j][k4 * 4];
#pragma unroll
                for (int i = 0; i < 4; ++i)
#pragma unroll
                    for (int j = 0; j < 4; ++j) {
                        ps[i][j] = __builtin_fmaf(av[i].x, wv[j].x, ps[i][j]);
                        ps[i][j] = __builtin_fmaf(av[i].y, wv[j].y, ps[i][j]);
                        ps[i][j] = __builtin_fmaf(av[i].z, wv[j].z, ps[i][j]);
                        ps[i][j] = __builtin_fmaf(av[i].w, wv[j].w, ps[i][j]);
                    }
            }
            if (c == 7 || c == 10) {
#pragma unroll
                for (int i = 0; i < 4; ++i)
#pragma unroll
                    for (int j = 0; j < 4; ++j) { s[i][j] += ps[i][j]; ps[i][j] = 0.f; }
            }
        }
        lif_epilogue8(s, *thr0_p, m0state, spk0_bits, b, n0, myc * TC, tx, ty, ln);
    } else {
        const uint16_t* bsrc = spk0_bits + ((size_t)t_s * BATCH + b_s) * 64;
        const float* wsrc = W1 + (size_t)(n0 + sr) * H_DIM;
#pragma unroll 1
        for (int c = 0; c < 16; ++c) {           // joins c7 (512), c15 (1024)
            __syncthreads();
            {
                const uint32_t w = bsrc[c * 4 + q4];
#pragma unroll
                for (int u = 0; u < 4; ++u) {
                    float4 v;
                    v.x = ((w >> (u * 4 + 0)) & 1u) ? 1.0f : 0.0f;
                    v.y = ((w >> (u * 4 + 1)) & 1u) ? 1.0f : 0.0f;
                    v.z = ((w >> (u * 4 + 2)) & 1u) ? 1.0f : 0.0f;
                    v.w = ((w >> (u * 4 + 3)) & 1u) ? 1.0f : 0.0f;
                    *(float4*)&As[sr][(q4 * 4 + u) * 4] = v;
                }
#pragma unroll
                for (int u = 0; u < 4; ++u) {
                    const int f4 = q4 * 4 + u;
                    const float4 wv = *(const float4*)(wsrc + c * 64 + f4 * 4);
                    *(float4*)&Ws[sr][f4 * 4] = wv;
                }
            }
            __syncthreads();
            for (int k4 = 0; k4 < 16; ++k4) {
                float4 av[4], wv[4];
#pragma unroll
                for (int i = 0; i < 4; ++i)
                    av[i] = *(const float4*)&As[4 * ty + i][k4 * 4];
#pragma unroll
                for (int j = 0; j < 4; ++j)
                    wv[j] = *(const float4*)&Ws[tx + 16 * j][k4 * 4];
#pragma unroll
                for (int i = 0; i < 4; ++i)
#pragma unroll
                    for (int j = 0; j < 4; ++j) {
                        ps[i][j] = __builtin_fmaf(av[i].x, wv[j].x, ps[i][j]);
                        ps[i][j] = __builtin_fmaf(av[i].y, wv[j].y, ps[i][j]);
                        ps[i][j] = __builtin_fmaf(av[i].z, wv[j].z, ps[i][j]);
                        ps[i][j] = __builtin_fmaf(av[i].w, wv[j].w, ps[i][j]);
                    }
            }
            if (c == 7 || c == 15) {
#pragma unroll
                for (int i = 0; i < 4; ++i)
#pragma unroll
                    for (int j = 0; j < 4; ++j) { s[i][j] += ps[i][j]; ps[i][j] = 0.f; }
            }
        }
        lif_epilogue8(s, *thr1_p, m1state, spk1_bits, b, n0, myc * TC, tx, ty, ln);
    }
}

// ---- K2a: output currents; thread = (q, n-quad, half-chain) ---------------
// Exact: half-chains are the BLIS panels; k2b joins them (s = fl(h0+h1)).
// Group-major gid -> each block's W2 working set is 8 KB (L1-resident).
__global__ __launch_bounds__(256) void k2a_gemm(
    const uint16_t* __restrict__ spk1_bits,
    const float* __restrict__ W2,     // [20][1024]
    float* __restrict__ cur2h)        // [2][25600][20]
{
    const int gid = blockIdx.x * 256 + threadIdx.x;   // 1000 blocks = 256000
    const int grp = gid / 25600;       // 0..9
    const int q   = gid % 25600;
    const int nq  = grp >> 1;          // n-quad 0..4
    const int h   = grp & 1;           // half-chain

    const uint16_t* bits = spk1_bits + (size_t)q * 64 + h * 32;
    const float* wr0 = W2 + (size_t)(nq * 4 + 0) * H_DIM + h * 512;
    const float* wr1 = W2 + (size_t)(nq * 4 + 1) * H_DIM + h * 512;
    const float* wr2 = W2 + (size_t)(nq * 4 + 2) * H_DIM + h * 512;
    const float* wr3 = W2 + (size_t)(nq * 4 + 3) * H_DIM + h * 512;

    float ps[4] = {0.f, 0.f, 0.f, 0.f};
    for (int wi = 0; wi < 32; ++wi) {
        const uint32_t bw = bits[wi];
        const int kb = wi * 16;
#pragma unroll
        for (int f = 0; f < 4; ++f) {
            const float4 a = *(const float4*)(wr0 + kb + f * 4);
            const float4 bq = *(const float4*)(wr1 + kb + f * 4);
            const float4 cq = *(const float4*)(wr2 + kb + f * 4);
            const float4 dq = *(const float4*)(wr3 + kb + f * 4);
            const int base = f * 4;
            ps[0] += ((bw >> (base + 0)) & 1u) ? a.x : 0.f;
            ps[1] += ((bw >> (base + 0)) & 1u) ? bq.x : 0.f;
            ps[2] += ((bw >> (base + 0)) & 1u) ? cq.x : 0.f;
            ps[3] += ((bw >> (base + 0)) & 1u) ? dq.x : 0.f;
            ps[0] += ((bw >> (base + 1)) & 1u) ? a.y : 0.f;
            ps[1] += ((bw >> (base + 1)) & 1u) ? bq.y : 0.f;
            ps[2] += ((bw >> (base + 1)) & 1u) ? cq.y : 0.f;
            ps[3] += ((bw >> (base + 1)) & 1u) ? dq.y : 0.f;
            ps[0] += ((bw >> (base + 2)) & 1u) ? a.z : 0.f;
            ps[1] += ((bw >> (base + 2)) & 1u) ? bq.z : 0.f;
            ps[2] += ((bw >> (base + 2)) & 1u) ? cq.z : 0.f;
            ps[3] += ((bw >> (base + 2)) & 1u) ? dq.z : 0.f;
            ps[0] += ((bw >> (base + 3)) & 1u) ? a.w : 0.f;
            ps[1] += ((bw >> (base + 3)) & 1u) ? bq.w : 0.f;
            ps[2] += ((bw >> (base + 3)) & 1u) ? cq.w : 0.f;
            ps[3] += ((bw >> (base + 3)) & 1u) ? dq.w : 0.f;
        }
    }
    float* dst = cur2h + ((size_t)h * 25600 + q) * OUT_DIM + nq * 4;
#pragma unroll
    for (int j = 0; j < 4; ++j) dst[j] = ps[j];
}

// ---- K2b: join halves (exact panel join) + LIF recurrence + final writes --
__global__ __launch_bounds__(256) void k2b_lif_out(
    const float* __restrict__ cur2h,   // [2][25600][20]
    const float* __restrict__ thr_p,
    float* __restrict__ out)           // [spk: 100*256*20][mem: 100*256*20]
{
    const int idx = blockIdx.x * 256 + threadIdx.x;
    if (idx >= BATCH * OUT_DIM) return;
    const float thr = *thr_p;
    const size_t stride = (size_t)BATCH * OUT_DIM;
    float m = 0.f;
    for (int t = 0; t < T_STEPS; ++t) {
        const float h0 = cur2h[(size_t)t * stride + idx];
        const float h1 = cur2h[(size_t)25600 * OUT_DIM + (size_t)t * stride + idx];
        const float cur = h0 + h1;             // BLIS join at k=512
        const float rst = (m > thr) ? thr : 0.f;
        float v = 0.5f * m + cur;
        v = v - rst;
        m = v;
        out[(size_t)t * stride + idx] = (v > thr) ? 1.0f : 0.0f;
        out[(size_t)T_STEPS * stride + (size_t)t * stride + idx] = v;
    }
}

extern "C" void kernel_launch(void* const* d_in, const int* in_sizes, int n_in,
                              void* d_out, int out_size, void* d_ws, size_t ws_size,
                              hipStream_t stream)
{
    const float* x    = (const float*)d_in[0];
    const float* W0   = (const float*)d_in[1];
    const float* W1   = (const float*)d_in[2];
    const float* W2   = (const float*)d_in[3];
    const float* thr0 = (const float*)d_in[4];
    const float* thr1 = (const float*)d_in[5];
    const float* thr2 = (const float*)d_in[6];

    // ws (12.75 MB): spk0 3.277 | spk1 3.277 | cur2h 4.096 | m0 1.049 | m1 1.049
    uint16_t* spk0_bits = (uint16_t*)d_ws;
    uint16_t* spk1_bits = spk0_bits + (size_t)T_STEPS * BATCH * 64;
    float*    cur2h     = (float*)(spk1_bits + (size_t)T_STEPS * BATCH * 64);
    float*    m0state   = cur2h + (size_t)2 * 25600 * OUT_DIM;
    float*    m1state   = m0state + (size_t)BATCH * H_DIM;

    hipMemsetAsync(m0state, 0, (size_t)BATCH * H_DIM * 2 * sizeof(float), stream);

    const dim3 grid(32, 32);                     // 1024 blocks: L0 | L1 pipelined
    for (int tc = 0; tc <= NCHUNK; ++tc)
        fused_l0_l1<<<grid, 256, 0, stream>>>(
            x, W0, W1, thr0, thr1, m0state, m1state, spk0_bits, spk1_bits, tc);

    k2a_gemm<<<1000, 256, 0, stream>>>(spk1_bits, W2, cur2h);
    k2b_lif_out<<<(BATCH * OUT_DIM + 255) / 256, 256, 0, stream>>>(
        cur2h, thr2, (float*)d_out);
}